// Round 8
// baseline (38.175 us; speedup 1.0000x reference)
//
#include <hip/hip_runtime.h>

// Embedding gather: out[i, :] = weight[x[i], :], i in [0, 64*512), EMBED=1000.
// Model M2 (verified round 6, absmax=0.0):
//   x int32[32768], weight f32[2548][1000] (10.2 MB, L2/L3-resident),
//   out f32[32768][1000] (131 MB) -> write-BW-bound.
// R6: 39.7us naive 1:1. R7: K=4 MLP + NT stores -> 37.9us (+5% only).
// R8 theory: block churn (8000 blocks x 16KB lifetime) + no steady-state
// load/store overlap. Fix: 2000 persistent blocks (31 waves/CU), 16 chunks
// per thread in 4 independent unrolled batches of 4; NT stores kept.

constexpr int VOCAB          = 2548;
constexpr int CHUNKS_PER_ROW = 250;                     // 1000 f32 = 250 x 16 B
constexpr int ROWS           = 64 * 512;                // 32768
constexpr int TOTAL_CHUNKS   = ROWS * CHUNKS_PER_ROW;   // 8,192,000
constexpr int BLOCKS         = 2000;
constexpr int THREADS        = 256;
constexpr int NTHR           = BLOCKS * THREADS;        // 512,000
constexpr int K              = TOTAL_CHUNKS / NTHR;     // 16, exact (no tail)

typedef unsigned int u32x4 __attribute__((ext_vector_type(4)));

__global__ __launch_bounds__(THREADS)
void embed_gather_f32_kernel(const int* __restrict__ x,
                             const u32x4* __restrict__ w,   // [VOCAB][250]
                             u32x4* __restrict__ out)       // [ROWS][250]
{
    const int c0 = blockIdx.x * THREADS + threadIdx.x;

    // 4 batches of 4 chunks; batches are independent -> loads of batch b+1
    // overlap the stores of batch b after full unroll.
    #pragma unroll
    for (int b = 0; b < K / 4; ++b) {
        int off[4], idx[4];
        u32x4 v[4];
        #pragma unroll
        for (int j = 0; j < 4; ++j) {
            const int c   = c0 + (b * 4 + j) * NTHR;
            const int row = c / CHUNKS_PER_ROW;          // magic-mul
            off[j] = c - row * CHUNKS_PER_ROW;
            idx[j] = min(max(x[row], 0), VOCAB - 1);     // L1-broadcast, clamped
        }
        #pragma unroll
        for (int j = 0; j < 4; ++j)
            v[j] = w[idx[j] * CHUNKS_PER_ROW + off[j]];
        #pragma unroll
        for (int j = 0; j < 4; ++j)
            __builtin_nontemporal_store(v[j], &out[c0 + (b * 4 + j) * NTHR]);
    }
}

extern "C" void kernel_launch(void* const* d_in, const int* in_sizes, int n_in,
                              void* d_out, int out_size, void* d_ws, size_t ws_size,
                              hipStream_t stream) {
    // x = smallest input (32768 elems), weight = largest (2,548,000 elems).
    int xi = 0, wi = 0;
    for (int i = 1; i < n_in; ++i) {
        if (in_sizes[i] < in_sizes[xi]) xi = i;
        if (in_sizes[i] > in_sizes[wi]) wi = i;
    }
    if (xi == wi && n_in >= 2) { xi = 0; wi = 1; }

    const int*   x = (const int*)d_in[xi];
    const u32x4* w = (const u32x4*)d_in[wi];
    u32x4*       o = (u32x4*)d_out;

    embed_gather_f32_kernel<<<BLOCKS, THREADS, 0, stream>>>(x, w, o);
}

// Round 9
// 35.147 us; speedup vs baseline: 1.0862x; 1.0862x over previous
//
#include <hip/hip_runtime.h>

// Embedding scatter (inverted gather): out[p,:] = weight[x[p],:].
// Model M2 (verified R6, absmax=0.0): x int32[32768], weight f32[2548][1000]
// (10.2 MB), out f32[32768][1000] (131 MB).
// R6/R7/R8 all ~38us = 262 MB (131 W + 131 R-miss) / 6.9 TB/s combined EA
// ceiling (= fill-kernel rate). Fix: group by vocab value -> weight read ONCE
// (10.2 MB), x scanned from L2 (cheap), writes unchanged. EA traffic 262->141MB.

constexpr int VOCAB   = 2548;
constexpr int ECHUNK  = 250;              // 1000 f32 = 250 x 16 B
constexpr int ROWS    = 64 * 512;         // 32768
constexpr int VPB     = 2;                // vocab rows per block
constexpr int GRID    = VOCAB / VPB;      // 1274, exact
constexpr int THREADS = 256;
constexpr int SEG     = 2048;             // x entries per scan segment
constexpr int NSEG    = ROWS / SEG;       // 16, exact

typedef unsigned int u32x4 __attribute__((ext_vector_type(4)));

__global__ __launch_bounds__(THREADS)
void embed_scatter_kernel(const int* __restrict__ x,
                          const u32x4* __restrict__ w,   // [VOCAB][250]
                          u32x4* __restrict__ out)       // [ROWS][250]
{
    __shared__ int q[VPB][SEG];           // position queues (cap=SEG: overflow
    __shared__ int qcnt[VPB];             //  is structurally impossible)
    const int v0 = blockIdx.x * VPB;
    const int t  = threadIdx.x;

    // Own rows -> registers, read exactly once per block (thread t = chunk t).
    u32x4 row[VPB];
    if (t < ECHUNK) {
        #pragma unroll
        for (int k = 0; k < VPB; ++k) row[k] = w[(v0 + k) * ECHUNK + t];
    }

    const int4* x4 = (const int4*)x;      // 16B-aligned index loads

    for (int s = 0; s < NSEG; ++s) {
        if (t < VPB) qcnt[t] = 0;
        __syncthreads();

        // Scan this segment of x (L2-resident, coalesced int4 loads).
        #pragma unroll
        for (int u = 0; u < SEG / 4 / THREADS; ++u) {    // = 2
            const int i4   = s * (SEG / 4) + u * THREADS + t;
            const int4 xv  = x4[i4];
            const int base = i4 * 4;
            const int e[4] = { xv.x, xv.y, xv.z, xv.w };
            #pragma unroll
            for (int j = 0; j < 4; ++j) {
                const unsigned d = (unsigned)(e[j] - v0);
                if (d < (unsigned)VPB) {
                    const int slot = atomicAdd(&qcnt[d], 1);  // rare (~1.6/seg)
                    q[d][slot] = base + j;
                }
            }
        }
        __syncthreads();

        // Flush: block-wide coalesced NT stores of the register-held row.
        #pragma unroll
        for (int k = 0; k < VPB; ++k) {
            const int n = qcnt[k];
            for (int j = 0; j < n; ++j) {            // uniform branch (LDS cnt)
                const int p = q[k][j];
                if (t < ECHUNK)
                    __builtin_nontemporal_store(row[k], &out[p * ECHUNK + t]);
            }
        }
        __syncthreads();                  // protect qcnt/q before next reset
    }
}

extern "C" void kernel_launch(void* const* d_in, const int* in_sizes, int n_in,
                              void* d_out, int out_size, void* d_ws, size_t ws_size,
                              hipStream_t stream) {
    // x = smallest input (32768 elems), weight = largest (2,548,000 elems).
    int xi = 0, wi = 0;
    for (int i = 1; i < n_in; ++i) {
        if (in_sizes[i] < in_sizes[xi]) xi = i;
        if (in_sizes[i] > in_sizes[wi]) wi = i;
    }
    if (xi == wi && n_in >= 2) { xi = 0; wi = 1; }

    const int*   x = (const int*)d_in[xi];
    const u32x4* w = (const u32x4*)d_in[wi];
    u32x4*       o = (u32x4*)d_out;

    embed_scatter_kernel<<<GRID, THREADS, 0, stream>>>(x, w, o);
}